// Round 1
// baseline (2382.389 us; speedup 1.0000x reference)
//
#include <hip/hip_runtime.h>
#include <math.h>

#define BATCH 32
#define T 2048
#define D 1024
#define KW 31
#define CPAD 15
#define KEXT 62      // 2*31 conv-patch columns
#define KTOT 1088    // 1024 + 64 (62 + 2 zero pad), multiple of BK

#define BM 64
#define BN 64
#define BK 16

// ---------------- K1: q = query @ Wq^T  ([B,D]) ----------------
__global__ __launch_bounds__(256) void k_q(const float* __restrict__ query,
                                           const float* __restrict__ Wq,
                                           float* __restrict__ qout) {
    int b = blockIdx.y;
    int w = threadIdx.x >> 6;
    int lane = threadIdx.x & 63;
    int d = blockIdx.x * 4 + w;
    const float* qrow = query + (size_t)b * D;
    const float* wrow = Wq + (size_t)d * D;
    float s = 0.f;
    #pragma unroll
    for (int i = 0; i < D / 64; ++i) s += qrow[lane + i * 64] * wrow[lane + i * 64];
    #pragma unroll
    for (int off = 32; off > 0; off >>= 1) s += __shfl_down(s, off, 64);
    if (lane == 0) qout[(size_t)b * D + d] = s;
}

// ---------------- K2: fused (memory@Wm^T + conv-loc) -> tanh -> dot v -> e_part ----------------
// A_ext[t, kk] : kk<1024 -> memory[b,t,kk] ; kk>=1024 -> conv patch of prev/cum
// B_ext[d, kk] : kk<1024 -> Wm[d,kk]       ; kk>=1024 -> Wloc[d, c, k]
// e_part[(b*T+t)*16 + dchunk] = sum_{d in chunk} tanh(acc + q[b,d]) * v[d]
__global__ __launch_bounds__(256) void k_gemm_e(
    const float* __restrict__ memory, const float* __restrict__ Wm,
    const float* __restrict__ Wloc, const float* __restrict__ prev,
    const float* __restrict__ cum, const float* __restrict__ qv,
    const float* __restrict__ vvec, float* __restrict__ e_part) {
    __shared__ float As[BK][68];   // [k][t], padded to 68 (16B-aligned rows, conflict-light)
    __shared__ float Bs[BK][68];   // [k][d]

    const int t0 = blockIdx.x * BM;
    const int d0 = blockIdx.y * BN;
    const int b  = blockIdx.z;
    const int tid = threadIdx.x;
    const int tx = tid & 15, ty = tid >> 4;
    const int lr = tid >> 2;      // load row 0..63
    const int lc4 = tid & 3;      // float4 column group

    float acc[4][4] = {{0.f}};

    const float* Abase = memory + ((size_t)b * T + t0) * D;
    const float* pb = prev + (size_t)b * T;
    const float* cb = cum  + (size_t)b * T;

    for (int k0 = 0; k0 < KTOT; k0 += BK) {
        if (k0 < D) {
            const float4 a4 = *(const float4*)(Abase + (size_t)lr * D + k0 + lc4 * 4);
            As[lc4 * 4 + 0][lr] = a4.x;
            As[lc4 * 4 + 1][lr] = a4.y;
            As[lc4 * 4 + 2][lr] = a4.z;
            As[lc4 * 4 + 3][lr] = a4.w;
            const float4 b4 = *(const float4*)(Wm + (size_t)(d0 + lr) * D + k0 + lc4 * 4);
            Bs[lc4 * 4 + 0][lr] = b4.x;
            Bs[lc4 * 4 + 1][lr] = b4.y;
            Bs[lc4 * 4 + 2][lr] = b4.z;
            Bs[lc4 * 4 + 3][lr] = b4.w;
        } else {
            const int t = t0 + lr;
            const int d = d0 + lr;
            #pragma unroll
            for (int u = 0; u < 4; ++u) {
                const int j = k0 + lc4 * 4 + u - D;   // 0..63
                float av = 0.f, bv = 0.f;
                if (j < KEXT) {
                    const int cch = (j >= KW) ? 1 : 0;
                    const int kp  = j - cch * KW;
                    const int ts  = t + kp - CPAD;
                    if (ts >= 0 && ts < T)
                        av = (cch == 0) ? pb[ts] : cb[ts];
                    bv = Wloc[((size_t)d * 2 + cch) * KW + kp];
                }
                As[lc4 * 4 + u][lr] = av;
                Bs[lc4 * 4 + u][lr] = bv;
            }
        }
        __syncthreads();
        #pragma unroll
        for (int kk = 0; kk < BK; ++kk) {
            const float4 av = *(const float4*)&As[kk][ty * 4];
            const float4 bv = *(const float4*)&Bs[kk][tx * 4];
            acc[0][0] += av.x * bv.x; acc[0][1] += av.x * bv.y;
            acc[0][2] += av.x * bv.z; acc[0][3] += av.x * bv.w;
            acc[1][0] += av.y * bv.x; acc[1][1] += av.y * bv.y;
            acc[1][2] += av.y * bv.z; acc[1][3] += av.y * bv.w;
            acc[2][0] += av.z * bv.x; acc[2][1] += av.z * bv.y;
            acc[2][2] += av.z * bv.z; acc[2][3] += av.z * bv.w;
            acc[3][0] += av.w * bv.x; acc[3][1] += av.w * bv.y;
            acc[3][2] += av.w * bv.z; acc[3][3] += av.w * bv.w;
        }
        __syncthreads();
    }

    // epilogue: tanh(acc + q) * v, reduce over the 64 d-columns of this block
    float qreg[4], vreg[4];
    #pragma unroll
    for (int j = 0; j < 4; ++j) {
        const int d = d0 + tx * 4 + j;
        qreg[j] = qv[(size_t)b * D + d];
        vreg[j] = vvec[d];
    }
    float rsum[4];
    #pragma unroll
    for (int i = 0; i < 4; ++i) {
        float s = 0.f;
        #pragma unroll
        for (int j = 0; j < 4; ++j)
            s += tanhf(acc[i][j] + qreg[j]) * vreg[j];
        rsum[i] = s;
    }
    // threads sharing the same rows are the 16 tx values within a 16-lane group
    #pragma unroll
    for (int i = 0; i < 4; ++i)
        #pragma unroll
        for (int off = 8; off > 0; off >>= 1)
            rsum[i] += __shfl_down(rsum[i], off, 16);
    if (tx == 0) {
        const int dch = blockIdx.y;   // 0..15
        #pragma unroll
        for (int i = 0; i < 4; ++i) {
            const int t = t0 + ty * 4 + i;
            e_part[((size_t)b * T + t) * 16 + dch] = rsum[i];
        }
    }
}

// ---------------- K3: masked softmax over T per batch, writes a ----------------
__global__ __launch_bounds__(256) void k_softmax(const float* __restrict__ e_part,
                                                 const int* __restrict__ mask,
                                                 float* __restrict__ aout) {
    const int b = blockIdx.x;
    const int tid = threadIdx.x;
    __shared__ float red[256];
    float ev[8];
    float lmax = -INFINITY;
    #pragma unroll
    for (int i = 0; i < 8; ++i) {
        const int t = tid + i * 256;
        const float* p = e_part + ((size_t)b * T + t) * 16;
        float s = 0.f;
        #pragma unroll
        for (int c = 0; c < 16; ++c) s += p[c];
        if (mask[(size_t)b * T + t] != 0) s = -INFINITY;   // mask==True -> -inf
        ev[i] = s;
        lmax = fmaxf(lmax, s);
    }
    red[tid] = lmax; __syncthreads();
    for (int off = 128; off > 0; off >>= 1) {
        if (tid < off) red[tid] = fmaxf(red[tid], red[tid + off]);
        __syncthreads();
    }
    const float mx = red[0]; __syncthreads();
    float lsum = 0.f;
    #pragma unroll
    for (int i = 0; i < 8; ++i) {
        const float x = expf(ev[i] - mx);  // exp(-inf) = 0
        ev[i] = x;
        lsum += x;
    }
    red[tid] = lsum; __syncthreads();
    for (int off = 128; off > 0; off >>= 1) {
        if (tid < off) red[tid] += red[tid + off];
        __syncthreads();
    }
    const float inv = 1.f / red[0];
    #pragma unroll
    for (int i = 0; i < 8; ++i)
        aout[(size_t)b * T + tid + i * 256] = ev[i] * inv;
}

// ---------------- K4: partial ctx over t-chunks (deterministic, no atomics) ----------------
__global__ __launch_bounds__(256) void k_ctx_part(const float* __restrict__ memory,
                                                  const float* __restrict__ a,
                                                  float* __restrict__ ctx_part) {
    const int b = blockIdx.x;
    const int tc = blockIdx.y;       // 0..7, 256 t each
    const int d4 = threadIdx.x * 4;
    float4 acc = make_float4(0.f, 0.f, 0.f, 0.f);
    const float* mb = memory + ((size_t)b * T + (size_t)tc * 256) * D;
    const float* ab = a + (size_t)b * T + (size_t)tc * 256;
    for (int t = 0; t < 256; ++t) {
        const float w = ab[t];
        const float4 m4 = *(const float4*)(mb + (size_t)t * D + d4);
        acc.x += w * m4.x; acc.y += w * m4.y;
        acc.z += w * m4.z; acc.w += w * m4.w;
    }
    *(float4*)(ctx_part + ((size_t)(b * 8 + tc)) * D + d4) = acc;
}

// ---------------- K5: reduce ctx partials -> ctx ----------------
__global__ __launch_bounds__(256) void k_ctx_red(const float* __restrict__ ctx_part,
                                                 float* __restrict__ ctx) {
    const int idx = blockIdx.x * 256 + threadIdx.x;  // over B*D
    const int b = idx >> 10, d = idx & 1023;
    float s = 0.f;
    #pragma unroll
    for (int tc = 0; tc < 8; ++tc) s += ctx_part[((size_t)(b * 8 + tc)) * D + d];
    ctx[idx] = s;
}

extern "C" void kernel_launch(void* const* d_in, const int* in_sizes, int n_in,
                              void* d_out, int out_size, void* d_ws, size_t ws_size,
                              hipStream_t stream) {
    const float* query  = (const float*)d_in[0];
    const float* memory = (const float*)d_in[1];
    const float* prev   = (const float*)d_in[2];
    const float* cum    = (const float*)d_in[3];
    const int*   mask   = (const int*)d_in[4];    // bool -> int32 per harness convention
    const float* Wq     = (const float*)d_in[5];
    const float* Wm     = (const float*)d_in[6];
    const float* Wloc   = (const float*)d_in[7];
    const float* v      = (const float*)d_in[8];

    float* out = (float*)d_out;
    float* ctx = out;               // [B, D]
    float* a   = out + BATCH * D;   // [B, T]

    char* ws = (char*)d_ws;
    float* qv       = (float*)ws;                                   // 128 KB
    float* e_part   = (float*)(ws + 131072);                        // 4 MB  [B,T,16]
    float* ctx_part = (float*)(ws + 131072 + 4194304);              // 1 MB  [B,8,D]

    k_q<<<dim3(D / 4, BATCH), 256, 0, stream>>>(query, Wq, qv);
    k_gemm_e<<<dim3(T / BM, D / BN, BATCH), 256, 0, stream>>>(memory, Wm, Wloc, prev,
                                                              cum, qv, v, e_part);
    k_softmax<<<BATCH, 256, 0, stream>>>(e_part, mask, a);
    k_ctx_part<<<dim3(BATCH, 8), 256, 0, stream>>>(memory, a, ctx_part);
    k_ctx_red<<<(BATCH * D) / 256, 256, 0, stream>>>(ctx_part, ctx);
}

// Round 2
// 880.491 us; speedup vs baseline: 2.7057x; 2.7057x over previous
//
#include <hip/hip_runtime.h>
#include <math.h>

#define BATCH 32
#define T 2048
#define D 1024
#define KW 31
#define CPAD 15
#define KEXT 62      // 2*31 conv-patch columns
#define KTOT 1088    // 1024 + 64 (62 + 2 zero pad)
#define BM 128
#define BN 128
#define BK 32

typedef __bf16 bf16_8 __attribute__((ext_vector_type(8)));
typedef float  f32x4  __attribute__((ext_vector_type(4)));

__device__ __forceinline__ float tanh_fast(float x) {
    // 1 - 2/(exp(2x)+1): exp->inf => 1, exp->0 => -1 (NaN-safe at extremes)
    return 1.f - 2.f * __builtin_amdgcn_rcpf(__expf(2.f * x) + 1.f);
}

// ---------------- K1: q = query @ Wq^T  ([B,D]) ----------------
__global__ __launch_bounds__(256) void k_q(const float* __restrict__ query,
                                           const float* __restrict__ Wq,
                                           float* __restrict__ qout) {
    int b = blockIdx.y;
    int w = threadIdx.x >> 6;
    int lane = threadIdx.x & 63;
    int d = blockIdx.x * 4 + w;
    const float* qrow = query + (size_t)b * D;
    const float* wrow = Wq + (size_t)d * D;
    float s = 0.f;
    #pragma unroll
    for (int i = 0; i < D / 64; ++i) s += qrow[lane + i * 64] * wrow[lane + i * 64];
    #pragma unroll
    for (int off = 32; off > 0; off >>= 1) s += __shfl_down(s, off, 64);
    if (lane == 0) qout[(size_t)b * D + d] = s;
}

// ---------------- K2: bf16 MFMA fused GEMM + tanh·v epilogue -> e_part ----------------
// A_ext[t,kk]: kk<1024 -> memory[b,t,kk]; kk>=1024 -> conv patch of prev/cum
// B_ext[d,kk]: kk<1024 -> Wm[d,kk];       kk>=1024 -> Wloc[d,c,k]
// LDS fragment-major: group g (16 rows), chunk id within group = lane (q=lane>>4,m=lane&15)
// holds A[g*16+m][k0+q*8 .. +7] as bf16x8. ds_read/ds_write are lane-contiguous.
__global__ __launch_bounds__(256) void k_gemm_e(
    const float* __restrict__ memory, const float* __restrict__ Wm,
    const float* __restrict__ Wloc, const float* __restrict__ prev,
    const float* __restrict__ cum, const float* __restrict__ qv,
    const float* __restrict__ vvec, float* __restrict__ e_part) {
    __shared__ bf16_8 As[8 * 64];   // 8 groups x 64 chunks x 16B = 8 KB
    __shared__ bf16_8 Bs[8 * 64];

    const int t0 = blockIdx.x * BM;
    const int d0 = blockIdx.y * BN;
    const int b  = blockIdx.z;
    const int tid  = threadIdx.x;
    const int lane = tid & 63;
    const int w    = tid >> 6;       // wave 0..3
    const int wr   = w >> 1;         // row half (t)
    const int wc   = w & 1;          // col half (d)
    const int q    = lane >> 4;      // quad
    const int m    = lane & 15;

    f32x4 acc[4][4] = {};

    const float* Abase = memory + ((size_t)b * T + t0) * (size_t)D;
    const float* Bbase = Wm + (size_t)d0 * D;
    const float* pb = prev + (size_t)b * T;
    const float* cb = cum  + (size_t)b * T;

    for (int k0 = 0; k0 < KTOT; k0 += BK) {
        if (k0 < D) {
            #pragma unroll
            for (int s = 0; s < 2; ++s) {
                const int g = w + s * 4;
                {
                    const float* src = Abase + (size_t)(g * 16 + m) * D + k0 + q * 8;
                    const float4 x = *(const float4*)src;
                    const float4 y = *(const float4*)(src + 4);
                    bf16_8 c;
                    c[0] = (__bf16)x.x; c[1] = (__bf16)x.y; c[2] = (__bf16)x.z; c[3] = (__bf16)x.w;
                    c[4] = (__bf16)y.x; c[5] = (__bf16)y.y; c[6] = (__bf16)y.z; c[7] = (__bf16)y.w;
                    As[g * 64 + lane] = c;
                }
                {
                    const float* src = Bbase + (size_t)(g * 16 + m) * D + k0 + q * 8;
                    const float4 x = *(const float4*)src;
                    const float4 y = *(const float4*)(src + 4);
                    bf16_8 c;
                    c[0] = (__bf16)x.x; c[1] = (__bf16)x.y; c[2] = (__bf16)x.z; c[3] = (__bf16)x.w;
                    c[4] = (__bf16)y.x; c[5] = (__bf16)y.y; c[6] = (__bf16)y.z; c[7] = (__bf16)y.w;
                    Bs[g * 64 + lane] = c;
                }
            }
        } else {
            #pragma unroll
            for (int s = 0; s < 2; ++s) {
                const int g = w + s * 4;
                const int t = t0 + g * 16 + m;
                const int d = d0 + g * 16 + m;
                bf16_8 ca, cb8;
                #pragma unroll
                for (int jj = 0; jj < 8; ++jj) {
                    const int j = (k0 - D) + q * 8 + jj;   // 0..63
                    float av = 0.f, bv = 0.f;
                    if (j < KEXT) {
                        const int cch = (j >= KW) ? 1 : 0;
                        const int kp  = j - cch * KW;
                        const int ts  = t + kp - CPAD;
                        if (ts >= 0 && ts < T) av = cch ? cb[ts] : pb[ts];
                        bv = Wloc[((size_t)d * 2 + cch) * KW + kp];
                    }
                    ca[jj]  = (__bf16)av;
                    cb8[jj] = (__bf16)bv;
                }
                As[g * 64 + lane] = ca;
                Bs[g * 64 + lane] = cb8;
            }
        }
        __syncthreads();
        bf16_8 af[4], bfr[4];
        #pragma unroll
        for (int i = 0; i < 4; ++i) af[i]  = As[(wr * 4 + i) * 64 + lane];
        #pragma unroll
        for (int j = 0; j < 4; ++j) bfr[j] = Bs[(wc * 4 + j) * 64 + lane];
        #pragma unroll
        for (int i = 0; i < 4; ++i)
            #pragma unroll
            for (int j = 0; j < 4; ++j)
                acc[i][j] = __builtin_amdgcn_mfma_f32_16x16x32_bf16(af[i], bfr[j], acc[i][j], 0, 0, 0);
        __syncthreads();
    }

    // epilogue: e(t) += sum_d tanh(acc + q[d]) * v[d] over this wave's 64 d-cols
    float qreg[4], vreg[4];
    #pragma unroll
    for (int j = 0; j < 4; ++j) {
        const int d = d0 + wc * 64 + j * 16 + m;   // col = lane&15
        qreg[j] = qv[(size_t)b * D + d];
        vreg[j] = vvec[d];
    }
    const int dch = blockIdx.y * 2 + wc;           // 0..15
    #pragma unroll
    for (int i = 0; i < 4; ++i) {
        #pragma unroll
        for (int r = 0; r < 4; ++r) {
            float s = 0.f;
            #pragma unroll
            for (int j = 0; j < 4; ++j)
                s += tanh_fast(acc[i][j][r] + qreg[j]) * vreg[j];
            #pragma unroll
            for (int off = 8; off > 0; off >>= 1)
                s += __shfl_down(s, off, 16);
            if (m == 0) {
                const int t = t0 + wr * 64 + i * 16 + q * 4 + r;  // row = quad*4+reg
                e_part[((size_t)b * T + t) * 16 + dch] = s;
            }
        }
    }
}

// ---------------- K3: masked softmax over T per batch ----------------
__global__ __launch_bounds__(256) void k_softmax(const float* __restrict__ e_part,
                                                 const int* __restrict__ mask,
                                                 float* __restrict__ aout) {
    const int b = blockIdx.x;
    const int tid = threadIdx.x;
    __shared__ float red[256];
    float ev[8];
    float lmax = -INFINITY;
    #pragma unroll
    for (int i = 0; i < 8; ++i) {
        const int t = tid + i * 256;
        const float* p = e_part + ((size_t)b * T + t) * 16;
        float s = 0.f;
        #pragma unroll
        for (int c = 0; c < 16; ++c) s += p[c];
        if (mask[(size_t)b * T + t] != 0) s = -INFINITY;
        ev[i] = s;
        lmax = fmaxf(lmax, s);
    }
    red[tid] = lmax; __syncthreads();
    for (int off = 128; off > 0; off >>= 1) {
        if (tid < off) red[tid] = fmaxf(red[tid], red[tid + off]);
        __syncthreads();
    }
    const float mx = red[0]; __syncthreads();
    float lsum = 0.f;
    #pragma unroll
    for (int i = 0; i < 8; ++i) {
        const float x = expf(ev[i] - mx);
        ev[i] = x;
        lsum += x;
    }
    red[tid] = lsum; __syncthreads();
    for (int off = 128; off > 0; off >>= 1) {
        if (tid < off) red[tid] += red[tid + off];
        __syncthreads();
    }
    const float inv = 1.f / red[0];
    #pragma unroll
    for (int i = 0; i < 8; ++i)
        aout[(size_t)b * T + tid + i * 256] = ev[i] * inv;
}

// ---------------- K4: partial ctx over t-chunks (deterministic) ----------------
__global__ __launch_bounds__(256) void k_ctx_part(const float* __restrict__ memory,
                                                  const float* __restrict__ a,
                                                  float* __restrict__ ctx_part) {
    const int b = blockIdx.x;
    const int tc = blockIdx.y;       // 0..7
    const int d4 = threadIdx.x * 4;
    float4 acc = make_float4(0.f, 0.f, 0.f, 0.f);
    const float* mb = memory + ((size_t)b * T + (size_t)tc * 256) * D;
    const float* ab = a + (size_t)b * T + (size_t)tc * 256;
    for (int t = 0; t < 256; ++t) {
        const float wgt = ab[t];
        const float4 m4 = *(const float4*)(mb + (size_t)t * D + d4);
        acc.x += wgt * m4.x; acc.y += wgt * m4.y;
        acc.z += wgt * m4.z; acc.w += wgt * m4.w;
    }
    *(float4*)(ctx_part + ((size_t)(b * 8 + tc)) * D + d4) = acc;
}

// ---------------- K5: reduce ctx partials ----------------
__global__ __launch_bounds__(256) void k_ctx_red(const float* __restrict__ ctx_part,
                                                 float* __restrict__ ctx) {
    const int idx = blockIdx.x * 256 + threadIdx.x;
    const int b = idx >> 10, d = idx & 1023;
    float s = 0.f;
    #pragma unroll
    for (int tc = 0; tc < 8; ++tc) s += ctx_part[((size_t)(b * 8 + tc)) * D + d];
    ctx[idx] = s;
}

extern "C" void kernel_launch(void* const* d_in, const int* in_sizes, int n_in,
                              void* d_out, int out_size, void* d_ws, size_t ws_size,
                              hipStream_t stream) {
    const float* query  = (const float*)d_in[0];
    const float* memory = (const float*)d_in[1];
    const float* prev   = (const float*)d_in[2];
    const float* cum    = (const float*)d_in[3];
    const int*   mask   = (const int*)d_in[4];
    const float* Wq     = (const float*)d_in[5];
    const float* Wm     = (const float*)d_in[6];
    const float* Wloc   = (const float*)d_in[7];
    const float* v      = (const float*)d_in[8];

    float* out = (float*)d_out;
    float* ctx = out;               // [B, D]
    float* a   = out + BATCH * D;   // [B, T]

    char* ws = (char*)d_ws;
    float* qv       = (float*)ws;                                   // 128 KB
    float* e_part   = (float*)(ws + 131072);                        // 4 MB  [B,T,16]
    float* ctx_part = (float*)(ws + 131072 + 4194304);              // 1 MB  [B,8,D]

    k_q<<<dim3(D / 4, BATCH), 256, 0, stream>>>(query, Wq, qv);
    k_gemm_e<<<dim3(T / BM, D / BN, BATCH), 256, 0, stream>>>(memory, Wm, Wloc, prev,
                                                              cum, qv, v, e_part);
    k_softmax<<<BATCH, 256, 0, stream>>>(e_part, mask, a);
    k_ctx_part<<<dim3(BATCH, 8), 256, 0, stream>>>(memory, a, ctx_part);
    k_ctx_red<<<(BATCH * D) / 256, 256, 0, stream>>>(ctx_part, ctx);
}

// Round 3
// 759.692 us; speedup vs baseline: 3.1360x; 1.1590x over previous
//
#include <hip/hip_runtime.h>
#include <math.h>

#define BATCH 32
#define T 2048
#define D 1024
#define KW 31
#define CPAD 15
#define KEXT 62      // 2*31 conv-patch columns
#define KEXTP 64     // padded
#define KTOT 1088    // 1024 + 64
#define BM 128
#define BN 128
#define BK 32
#define NSTEP (KTOT / BK)   // 34

typedef __bf16 bf16_8 __attribute__((ext_vector_type(8)));
typedef __bf16 bf16_4 __attribute__((ext_vector_type(4)));
typedef float  f32x4  __attribute__((ext_vector_type(4)));

__device__ __forceinline__ float tanh_fast(float x) {
    return 1.f - 2.f * __builtin_amdgcn_rcpf(__expf(2.f * x) + 1.f);
}

__device__ __forceinline__ void glds16(const void* gsrc, void* ldst) {
    __builtin_amdgcn_global_load_lds(
        (const __attribute__((address_space(1))) unsigned int*)gsrc,
        (__attribute__((address_space(3))) unsigned int*)ldst, 16, 0, 0);
}

// ---------------- P1: Bext[d][kk] = bf16([Wm | Wloc]) ----------------
__global__ __launch_bounds__(256) void k_prep_b(const float* __restrict__ Wm,
                                                const float* __restrict__ Wloc,
                                                __bf16* __restrict__ Bext) {
    const int idx = blockIdx.x * 256 + threadIdx.x;   // 1088 blocks
    const int d = idx / (KTOT / 4);
    const int kk = (idx % (KTOT / 4)) * 4;
    bf16_4 o;
    #pragma unroll
    for (int u = 0; u < 4; ++u) {
        const int k = kk + u;
        float val = 0.f;
        if (k < D) val = Wm[(size_t)d * D + k];
        else {
            const int j = k - D;
            if (j < KEXT) {
                const int c = (j >= KW) ? 1 : 0;
                const int kp = j - c * KW;
                val = Wloc[((size_t)d * 2 + c) * KW + kp];
            }
        }
        o[u] = (__bf16)val;
    }
    *(bf16_4*)(Bext + (size_t)d * KTOT + kk) = o;
}

// ---------------- P2: Aloc[b][t][j] = bf16 conv patches ----------------
__global__ __launch_bounds__(256) void k_prep_aloc(const float* __restrict__ prev,
                                                   const float* __restrict__ cum,
                                                   __bf16* __restrict__ Aloc) {
    const int idx = blockIdx.x * 256 + threadIdx.x;   // 4096 blocks
    const int row = idx >> 4;          // b*T + t
    const int j0 = (idx & 15) * 4;
    const int b = row >> 11;
    const int t = row & (T - 1);
    bf16_4 o;
    #pragma unroll
    for (int u = 0; u < 4; ++u) {
        const int j = j0 + u;
        float val = 0.f;
        if (j < KEXT) {
            const int c = (j >= KW) ? 1 : 0;
            const int kp = j - c * KW;
            const int ts = t + kp - CPAD;
            if (ts >= 0 && ts < T)
                val = (c ? cum : prev)[(size_t)b * T + ts];
        }
        o[u] = (__bf16)val;
    }
    *(bf16_4*)(Aloc + (size_t)row * KEXTP + j0) = o;
}

// ---------------- K1: q = query @ Wq^T ----------------
__global__ __launch_bounds__(256) void k_q(const float* __restrict__ query,
                                           const float* __restrict__ Wq,
                                           float* __restrict__ qout) {
    int b = blockIdx.y;
    int w = threadIdx.x >> 6;
    int lane = threadIdx.x & 63;
    int d = blockIdx.x * 4 + w;
    const float* qrow = query + (size_t)b * D;
    const float* wrow = Wq + (size_t)d * D;
    float s = 0.f;
    #pragma unroll
    for (int i = 0; i < D / 64; ++i) s += qrow[lane + i * 64] * wrow[lane + i * 64];
    #pragma unroll
    for (int off = 32; off > 0; off >>= 1) s += __shfl_down(s, off, 64);
    if (lane == 0) qout[(size_t)b * D + d] = s;
}

// ---------------- K2: pipelined bf16 MFMA GEMM + tanh·v epilogue ----------------
// 3-deep LDS ring, 1 barrier/step. B + A-extension staged via global_load_lds
// (fragment-major layout = glds's base+lane*16 rule). A (fp32 memory) register-
// prefetched 1 step ahead, cvt+ds_write at step top.
__global__ __launch_bounds__(256, 3) void k_gemm_e(
    const float* __restrict__ memory, const __bf16* __restrict__ Aloc,
    const __bf16* __restrict__ Bext, const float* __restrict__ qv,
    const float* __restrict__ vvec, float* __restrict__ e_part) {
    __shared__ bf16_8 As[3][512];   // 3 x 8 KB
    __shared__ bf16_8 Bs[3][512];

    const int t0 = blockIdx.x * BM;
    const int d0 = blockIdx.y * BN;
    const int b  = blockIdx.z;
    const int tid  = threadIdx.x;
    const int lane = tid & 63;
    const int w    = tid >> 6;
    const int wr   = w >> 1, wc = w & 1;
    const int q    = lane >> 4, m = lane & 15;

    f32x4 acc[4][4] = {};

    const int g0 = w, g1 = w + 4;
    const size_t arow0 = (size_t)b * T + t0 + g0 * 16 + m;
    const size_t arow1 = (size_t)b * T + t0 + g1 * 16 + m;
    const float*  aptr0 = memory + arow0 * D + q * 8;
    const float*  aptr1 = memory + arow1 * D + q * 8;
    const __bf16* lptr0 = Aloc + arow0 * KEXTP + q * 8;
    const __bf16* lptr1 = Aloc + arow1 * KEXTP + q * 8;
    const __bf16* bptr0 = Bext + (size_t)(d0 + g0 * 16 + m) * KTOT + q * 8;
    const __bf16* bptr1 = Bext + (size_t)(d0 + g1 * 16 + m) * KTOT + q * 8;

    f32x4 pa[2][2];

    // prologue: B(0),B(1) async; A(0) regs -> As[0]
    glds16(bptr0,      &Bs[0][g0 * 64]);
    glds16(bptr1,      &Bs[0][g1 * 64]);
    glds16(bptr0 + BK, &Bs[1][g0 * 64]);
    glds16(bptr1 + BK, &Bs[1][g1 * 64]);
    pa[0][0] = *(const f32x4*)(aptr0);
    pa[0][1] = *(const f32x4*)(aptr0 + 4);
    pa[1][0] = *(const f32x4*)(aptr1);
    pa[1][1] = *(const f32x4*)(aptr1 + 4);
    {
        bf16_8 c0, c1;
        #pragma unroll
        for (int i = 0; i < 4; ++i) {
            c0[i] = (__bf16)pa[0][0][i]; c0[i + 4] = (__bf16)pa[0][1][i];
            c1[i] = (__bf16)pa[1][0][i]; c1[i + 4] = (__bf16)pa[1][1][i];
        }
        As[0][g0 * 64 + lane] = c0;
        As[0][g1 * 64 + lane] = c1;
    }

    for (int k = 0; k < NSTEP; ++k) {
        const int p = k % 3;
        if (k > 0 && k * BK < D) {       // A(k) cvt + LDS write (regs from step k-1)
            bf16_8 c0, c1;
            #pragma unroll
            for (int i = 0; i < 4; ++i) {
                c0[i] = (__bf16)pa[0][0][i]; c0[i + 4] = (__bf16)pa[0][1][i];
                c1[i] = (__bf16)pa[1][0][i]; c1[i + 4] = (__bf16)pa[1][1][i];
            }
            As[p][g0 * 64 + lane] = c0;
            As[p][g1 * 64 + lane] = c1;
        }
        __syncthreads();                 // drains glds for buf p + A writes
        const int ka = k + 1;
        if (ka < NSTEP) {
            const int ka0 = ka * BK;
            if (ka0 < D) {               // prefetch A(k+1) into regs
                pa[0][0] = *(const f32x4*)(aptr0 + ka0);
                pa[0][1] = *(const f32x4*)(aptr0 + ka0 + 4);
                pa[1][0] = *(const f32x4*)(aptr1 + ka0);
                pa[1][1] = *(const f32x4*)(aptr1 + ka0 + 4);
            } else {                     // conv-ext rows: already bf16, use glds
                glds16(lptr0 + (ka0 - D), &As[ka % 3][g0 * 64]);
                glds16(lptr1 + (ka0 - D), &As[ka % 3][g1 * 64]);
            }
        }
        const int kb = k + 2;
        if (kb < NSTEP) {                // B(k+2) async, distance 2
            glds16(bptr0 + kb * BK, &Bs[kb % 3][g0 * 64]);
            glds16(bptr1 + kb * BK, &Bs[kb % 3][g1 * 64]);
        }
        bf16_8 af[4], bfr[4];
        #pragma unroll
        for (int i = 0; i < 4; ++i) af[i]  = As[p][(wr * 4 + i) * 64 + lane];
        #pragma unroll
        for (int j = 0; j < 4; ++j) bfr[j] = Bs[p][(wc * 4 + j) * 64 + lane];
        #pragma unroll
        for (int i = 0; i < 4; ++i)
            #pragma unroll
            for (int j = 0; j < 4; ++j)
                acc[i][j] = __builtin_amdgcn_mfma_f32_16x16x32_bf16(af[i], bfr[j], acc[i][j], 0, 0, 0);
    }

    // epilogue: e(t) += sum_d tanh(acc + q[d]) * v[d]
    float qreg[4], vreg[4];
    #pragma unroll
    for (int j = 0; j < 4; ++j) {
        const int d = d0 + wc * 64 + j * 16 + m;
        qreg[j] = qv[(size_t)b * D + d];
        vreg[j] = vvec[d];
    }
    const int dch = blockIdx.y * 2 + wc;
    #pragma unroll
    for (int i = 0; i < 4; ++i) {
        #pragma unroll
        for (int r = 0; r < 4; ++r) {
            float s = 0.f;
            #pragma unroll
            for (int j = 0; j < 4; ++j)
                s += tanh_fast(acc[i][j][r] + qreg[j]) * vreg[j];
            #pragma unroll
            for (int off = 8; off > 0; off >>= 1)
                s += __shfl_down(s, off, 16);
            if (m == 0) {
                const int t = t0 + wr * 64 + i * 16 + q * 4 + r;
                e_part[((size_t)b * T + t) * 16 + dch] = s;
            }
        }
    }
}

// ---------------- K3: masked softmax over T ----------------
__global__ __launch_bounds__(256) void k_softmax(const float* __restrict__ e_part,
                                                 const int* __restrict__ mask,
                                                 float* __restrict__ aout) {
    const int b = blockIdx.x;
    const int tid = threadIdx.x;
    __shared__ float red[256];
    float ev[8];
    float lmax = -INFINITY;
    #pragma unroll
    for (int i = 0; i < 8; ++i) {
        const int t = tid + i * 256;
        const float* p = e_part + ((size_t)b * T + t) * 16;
        float s = 0.f;
        #pragma unroll
        for (int c = 0; c < 16; ++c) s += p[c];
        if (mask[(size_t)b * T + t] != 0) s = -INFINITY;
        ev[i] = s;
        lmax = fmaxf(lmax, s);
    }
    red[tid] = lmax; __syncthreads();
    for (int off = 128; off > 0; off >>= 1) {
        if (tid < off) red[tid] = fmaxf(red[tid], red[tid + off]);
        __syncthreads();
    }
    const float mx = red[0]; __syncthreads();
    float lsum = 0.f;
    #pragma unroll
    for (int i = 0; i < 8; ++i) {
        const float x = expf(ev[i] - mx);
        ev[i] = x;
        lsum += x;
    }
    red[tid] = lsum; __syncthreads();
    for (int off = 128; off > 0; off >>= 1) {
        if (tid < off) red[tid] += red[tid + off];
        __syncthreads();
    }
    const float inv = 1.f / red[0];
    #pragma unroll
    for (int i = 0; i < 8; ++i)
        aout[(size_t)b * T + tid + i * 256] = ev[i] * inv;
}

// ---------------- K4: partial ctx, 64-t chunks (1024 blocks) ----------------
__global__ __launch_bounds__(256) void k_ctx_part(const float* __restrict__ memory,
                                                  const float* __restrict__ a,
                                                  float* __restrict__ ctx_part) {
    const int b = blockIdx.x;
    const int tc = blockIdx.y;       // 0..31, 64 t each
    const int d4 = threadIdx.x * 4;
    f32x4 acc = {0.f, 0.f, 0.f, 0.f};
    const float* mb = memory + ((size_t)b * T + (size_t)tc * 64) * D;
    const float* ab = a + (size_t)b * T + (size_t)tc * 64;
    #pragma unroll 4
    for (int t = 0; t < 64; ++t) {
        const float wgt = ab[t];
        const f32x4 m4 = *(const f32x4*)(mb + (size_t)t * D + d4);
        acc += wgt * m4;
    }
    *(f32x4*)(ctx_part + ((size_t)(b * 32 + tc)) * D + d4) = acc;
}

// ---------------- K5: reduce 32 ctx partials ----------------
__global__ __launch_bounds__(256) void k_ctx_red(const float* __restrict__ ctx_part,
                                                 float* __restrict__ ctx) {
    const int idx = blockIdx.x * 256 + threadIdx.x;
    const int b = idx >> 10, d = idx & 1023;
    float s = 0.f;
    #pragma unroll
    for (int tc = 0; tc < 32; ++tc) s += ctx_part[((size_t)(b * 32 + tc)) * D + d];
    ctx[idx] = s;
}

extern "C" void kernel_launch(void* const* d_in, const int* in_sizes, int n_in,
                              void* d_out, int out_size, void* d_ws, size_t ws_size,
                              hipStream_t stream) {
    const float* query  = (const float*)d_in[0];
    const float* memory = (const float*)d_in[1];
    const float* prev   = (const float*)d_in[2];
    const float* cum    = (const float*)d_in[3];
    const int*   mask   = (const int*)d_in[4];
    const float* Wq     = (const float*)d_in[5];
    const float* Wm     = (const float*)d_in[6];
    const float* Wloc   = (const float*)d_in[7];
    const float* v      = (const float*)d_in[8];

    float* out = (float*)d_out;
    float* ctx = out;               // [B, D]
    float* a   = out + BATCH * D;   // [B, T]

    char* ws = (char*)d_ws;
    float*  qv       = (float*)(ws + 0);                 // 128 KB
    float*  e_part   = (float*)(ws + 131072);            // 4 MB   [B,T,16]
    float*  ctx_part = (float*)(ws + 4325376);           // 4 MB   [B,32,D]
    __bf16* Bext     = (__bf16*)(ws + 8519680);          // 2.23 MB [1024,1088]
    __bf16* Aloc     = (__bf16*)(ws + 10747904);         // 8 MB   [B,T,64]
    // total ~19.1 MB

    k_prep_b<<<KTOT * D / (256 * 4), 256, 0, stream>>>(Wm, Wloc, Bext);
    k_prep_aloc<<<BATCH * T * 16 / 256, 256, 0, stream>>>(prev, cum, Aloc);
    k_q<<<dim3(D / 4, BATCH), 256, 0, stream>>>(query, Wq, qv);
    k_gemm_e<<<dim3(T / BM, D / BN, BATCH), 256, 0, stream>>>(memory, Aloc, Bext,
                                                              qv, v, e_part);
    k_softmax<<<BATCH, 256, 0, stream>>>(e_part, mask, a);
    k_ctx_part<<<dim3(BATCH, 32), 256, 0, stream>>>(memory, a, ctx_part);
    k_ctx_red<<<(BATCH * D) / 256, 256, 0, stream>>>(ctx_part, ctx);
}